// Round 15
// baseline (176.478 us; speedup 1.0000x reference)
//
#include <hip/hip_runtime.h>
#include <hip/hip_bf16.h>

// Problem constants
constexpr int B  = 2;
constexpr int S  = 2048;
constexpr int E  = 1024;
constexpr int H  = 16;
constexpr int DK = 64;
constexpr int M  = B * S;            // 4096 rows of x
constexpr int N3 = 3 * E;            // stacked [Wk; Wv; Wq]
constexpr long RSZ = (long)B * H * S * DK;  // one output region (4.19M elems)

// Q scale: 1/sqrt(DK) * log2(e) -> softmax via raw v_exp_f32 (base-2), no mul.
#define QSCALE 0.18033688011112042f

using bf16x8 = __attribute__((ext_vector_type(8))) __bf16;
using bf16x4 = __attribute__((ext_vector_type(4))) __bf16;
using f32x4  = __attribute__((ext_vector_type(4))) float;

// async global->LDS, 16B/lane; LDS base wave-uniform, lane i lands at +i*16 B.
__device__ __forceinline__ void async16(__bf16* lds, const __bf16* g) {
    __builtin_amdgcn_global_load_lds(
        (const __attribute__((address_space(1))) void*)g,
        (__attribute__((address_space(3))) void*)lds, 16, 0, 0);
}

// ---------------- cvt: x and stacked W's -> bf16 (into d_out scratch) ----------------
__global__ __launch_bounds__(256)
void cvt_kernel(const float* __restrict__ x, const float* __restrict__ Wk,
                const float* __restrict__ Wv, const float* __restrict__ Wq,
                __bf16* __restrict__ xb, __bf16* __restrict__ wall) {
    const long total4 = ((long)M * E + (long)N3 * E) >> 2;   // 1,835,008
    const long stride = (long)gridDim.x * 256;
    for (long i4 = (long)blockIdx.x * 256 + threadIdx.x; i4 < total4; i4 += stride) {
        const long e = i4 * 4;
        const float* src;
        __bf16* dst;
        if (e < (long)M * E) { src = x + e; dst = xb + e; }
        else {
            const long e2 = e - (long)M * E;
            const int which = (int)(e2 >> 20);
            const long off  = e2 & ((1L << 20) - 1);
            src = (which == 0 ? Wk : which == 1 ? Wv : Wq) + off;
            dst = wall + e2;
        }
        float4 f = *reinterpret_cast<const float4*>(src);
        bf16x4 o;
        o[0] = (__bf16)f.x; o[1] = (__bf16)f.y; o[2] = (__bf16)f.z; o[3] = (__bf16)f.w;
        *reinterpret_cast<bf16x4*>(dst) = o;
    }
}

// ---------------- QKV GEMM v9: 256x256 tile, K-half counted-vmcnt pipeline ----------------
// R14 accounting: v7 (128^2) costs ~750 B LDS-traffic per MFMA (A shared by 2
// waves, B by 2) and re-reads 403 MB of panels. 256^2 with 8 waves: A shared
// by 4, B by 2 -> 375 B/MFMA, panel re-reads 201 MB. Structure (derived from
// the 8-phase template, guide S5):
//   BK=64 staged as two 32-col K-halves; LDS = 2 buf x {A,B} x {h0,h1} x
//   (256x32 bf16 = 16 KB) = 128 KB; 512 thr, 8 waves (2M x 4N), per-wave
//   output 128x64 (acc 8x4 f32x4 = 128 VGPR).
// Counted-vmcnt invariant (4 issues per half-stage, per wave):
//   entry to step kt: outstanding = {kt.h1(4), kt+1.h0(4)}, kt.h0 drained.
//   phase A: stage kt+1.h1 (+4=12) -> MFMA(kt.h0) -> vmcnt(8) drains kt.h1
//            -> barrier.
//   phase B: stage kt+2.h0 into buf cur (+4=12; WAR safe: kt.h0's readers all
//            passed the phase-A barrier) -> MFMA(kt.h1) -> vmcnt(8) drains
//            kt+1.h0 -> barrier.   Tail: vmcnt(4)@kt=14B, vmcnt(0)@kt=15A.
// Swizzle: LDS(row, pc) holds global chunk pc^(row&3); frag read chunk =
// quad^(l16&3) -> retrieves global chunk quad; lanes 0-7 cover banks 0-31
// exactly once (verified), 16 lanes = 2-way = free.
// Epilogues: per-wave private 16 KB LDS bounce (8x16=128 KB, no barriers),
// coalesced b128 stores; V^T transposed in-bounce; Q applies cos in-bounce.
__global__ __launch_bounds__(512, 1)
void qkv_gemm(const __bf16* __restrict__ xb, const __bf16* __restrict__ wall,
              const float* __restrict__ theta, __bf16* __restrict__ kvq) {
    __shared__ __align__(1024) __bf16 smem[8 * 8192];   // 128 KB

    const int t    = threadIdx.x;
    const int lane = t & 63;
    const int w    = t >> 6;            // 0..7
    const int quad = lane >> 4;
    const int l16  = lane & 15;
    const int wr   = w >> 2, wc = w & 3;   // 2x4 wave grid, 128x64 each

    const int bx   = blockIdx.x;        // 0..191
    const int mt   = bx & 15;           // 16 M-tiles
    const int nt2  = bx >> 4;           // 12 N-tiles
    const int mbase = mt * 256;
    const int nbase = nt2 * 256;
    const int region = nt2 >> 2;        // block-uniform 0=K 1=V 2=Q

    f32x4 acc[8][4];
    #pragma unroll
    for (int i = 0; i < 8; i++)
        #pragma unroll
        for (int j = 0; j < 4; j++)
            acc[i][j] = f32x4{0.f, 0.f, 0.f, 0.f};

    // staging: slot = i*512 + w*64 + lane; row = i*128 + w*16 + (lane>>2);
    // phys chunk (lane&3) holds global chunk (lane&3)^(row&3) = (lane&3)^((lane>>2)&3).
    const int srowL = lane >> 2;
    const int slc   = (lane & 3) ^ (srowL & 3);
    const __bf16* srcA = xb   + (long)(mbase + w * 16 + srowL) * E + slc * 8;
    const __bf16* srcB = wall + (long)(nbase + w * 16 + srowL) * E + slc * 8;

    // half-tile LDS base: ((buf*2 + mat)*2 + kh) * 8192 elems (16 KB each)
    auto stage = [&](int buf, int kh, int kt) {   // 4 issues per wave
        const long koff = (long)kt * 64 + kh * 32;
        #pragma unroll
        for (int i = 0; i < 2; i++) {
            async16(smem + ((buf * 2 + 0) * 2 + kh) * 8192 + (i * 512 + w * 64) * 8,
                    srcA + (long)i * 128 * E + koff);
            async16(smem + ((buf * 2 + 1) * 2 + kh) * 8192 + (i * 512 + w * 64) * 8,
                    srcB + (long)i * 128 * E + koff);
        }
    };

    // prologue: t0.h0, t0.h1, t1.h0 (12 outstanding) -> drain t0.h0
    stage(0, 0, 0);
    stage(0, 1, 0);
    stage(1, 0, 1);
    asm volatile("s_waitcnt vmcnt(8)" ::: "memory");
    asm volatile("s_barrier" ::: "memory");

    const int ck = (quad ^ (l16 & 3)) * 8;   // frag chunk byte-offset (elems)

    for (int kt = 0; kt < 16; kt++) {
        const int cur = kt & 1;
        #pragma unroll
        for (int kh = 0; kh < 2; kh++) {
            // stage issues first (max latency cover)
            if (kh == 0) { if (kt + 1 < 16) stage(1 - cur, 1, kt + 1); }
            else         { if (kt + 2 < 16) stage(cur,     0, kt + 2); }

            const __bf16* Ah = smem + ((cur * 2 + 0) * 2 + kh) * 8192;
            const __bf16* Bh = smem + ((cur * 2 + 1) * 2 + kh) * 8192;
            bf16x8 a[8], b[4];
            #pragma unroll
            for (int mi = 0; mi < 8; mi++)
                a[mi] = *reinterpret_cast<const bf16x8*>(
                    &Ah[(wr * 128 + mi * 16 + l16) * 32 + ck]);
            #pragma unroll
            for (int ni = 0; ni < 4; ni++)
                b[ni] = *reinterpret_cast<const bf16x8*>(
                    &Bh[(wc * 64 + ni * 16 + l16) * 32 + ck]);

            __builtin_amdgcn_s_setprio(1);
            #pragma unroll
            for (int mi = 0; mi < 8; mi++)
                #pragma unroll
                for (int ni = 0; ni < 4; ni++)
                    acc[mi][ni] = __builtin_amdgcn_mfma_f32_16x16x32_bf16(
                        a[mi], b[ni], acc[mi][ni], 0, 0, 0);
            __builtin_amdgcn_s_setprio(0);

            // counted waits (see invariant above)
            if (kh == 0) {
                if (kt < 15) asm volatile("s_waitcnt vmcnt(8)" ::: "memory");
                else         asm volatile("s_waitcnt vmcnt(0)" ::: "memory");
            } else {
                if (kt < 14)       asm volatile("s_waitcnt vmcnt(8)" ::: "memory");
                else if (kt == 14) asm volatile("s_waitcnt vmcnt(4)" ::: "memory");
            }
            asm volatile("s_barrier" ::: "memory");
        }
    }

    // ---- epilogue: per-wave private 16 KB scratch (no cross-wave hazards) ----
    __syncthreads();                       // all LDS/DMA quiesced
    __bf16* scr = smem + w * 8192;
    const int bb = mbase >> 11;
    const int h  = (nt2 & 3) * 4 + wc;     // wave's single head
    if (region == 1) {
        // V: bounce transposed [d 64][s 128] (b64 writes), store d-rows
        #pragma unroll
        for (int mi = 0; mi < 8; mi++)
            #pragma unroll
            for (int ni = 0; ni < 4; ni++) {
                bf16x4 pk;
                #pragma unroll
                for (int r = 0; r < 4; r++) pk[r] = (__bf16)acc[mi][ni][r];
                *reinterpret_cast<bf16x4*>(
                    &scr[(ni * 16 + l16) * 128 + mi * 16 + quad * 4]) = pk;
            }
        __bf16* vt = kvq + RSZ;            // V^T region: [B,H,DK,S]
        const long vbase = ((long)(bb * 16 + h) * 64) * 2048 + (mbase & 2047) + wr * 128;
        #pragma unroll
        for (int i = 0; i < 16; i++) {
            const int d  = i * 4 + (lane >> 4);
            const int sc = lane & 15;
            bf16x8 v = *reinterpret_cast<const bf16x8*>(&scr[d * 128 + sc * 8]);
            *reinterpret_cast<bf16x8*>(&vt[vbase + (long)d * 2048 + sc * 8]) = v;
        }
    } else {
        // K/Q: bounce [row 128][col 64], apply cos for Q, store row-chunks
        __bf16* dst = kvq + (region == 2 ? 2 * RSZ : 0);
        float th[4];
        if (region == 2) {
            #pragma unroll
            for (int ni = 0; ni < 4; ni++) th[ni] = theta[ni * 16 + l16];
        }
        #pragma unroll
        for (int mi = 0; mi < 8; mi++)
            #pragma unroll
            for (int ni = 0; ni < 4; ni++)
                #pragma unroll
                for (int r = 0; r < 4; r++) {
                    float v = acc[mi][ni][r];
                    if (region == 2) v = cosf(v + th[ni]) * QSCALE;
                    scr[(mi * 16 + quad * 4 + r) * 64 + ni * 16 + l16] = (__bf16)v;
                }
        const int s0 = mbase + wr * 128;
        #pragma unroll
        for (int i = 0; i < 16; i++) {
            const int row   = i * 8 + (lane >> 3);
            const int chunk = lane & 7;
            bf16x8 v = *reinterpret_cast<const bf16x8*>(&scr[row * 64 + chunk * 8]);
            const int s = (s0 + row) & 2047;
            *reinterpret_cast<bf16x8*>(
                &dst[((long)(bb * 16 + h) * 2048 + s) * 64 + chunk * 8]) = v;
        }
    }
}

// ---------------- attention v16 (R14-verified 51.6us): v10 loop + setprio ----------------
__global__ __launch_bounds__(256, 2)
void attn_kernel(const __bf16* __restrict__ q_ws, const __bf16* __restrict__ k_ws,
                 const __bf16* __restrict__ v_ws, float* __restrict__ out) {
    __shared__ __align__(1024) __bf16 Ks[3][64 * 64];   // [key][d] swizzled, 8 KB each
    __shared__ __align__(1024) __bf16 Vs[3][64 * 64];   // [d][key] swizzled, 8 KB each
    __shared__ __align__(16)   __bf16 Pl[4][32 * 72];   // per-wave P [qrow][key], stride 72
    __shared__ __align__(16)   float  ls_lds[4][32];

    const int lane = threadIdx.x & 63;
    const int w    = threadIdx.x >> 6;          // 0..3
    const int quad = lane >> 4;
    const int l16  = lane & 15;

    // XCD swizzle: 4 bh per id%8 class -> per-XCD K/V set 2MB < 4MB L2 (R6-verified)
    const int id    = blockIdx.x;
    const int bh    = (id & 7) + 8 * ((id >> 3) & 3);
    const int qbase = (id >> 5) * 128 + w * 32;  // wave owns 32 q-rows

    const __bf16* qp = q_ws + (long)bh * S * DK;
    const __bf16* kp = k_ws + (long)bh * S * DK;
    const __bf16* vp = v_ws + (long)bh * DK * S;   // [DK][S]

    // staging: 8 rows x 8 chunks(16B) per async16; source chunk XOR-swizzled
    const int sr  = lane >> 3;
    const int scs = (lane & 7) ^ sr;

    // Q B-frags resident: B[k=d=ks*32+quad*8+j][n=qrow=nt*16+l16]
    bf16x8 bq[2][2];
    #pragma unroll
    for (int nt = 0; nt < 2; nt++)
        #pragma unroll
        for (int ks = 0; ks < 2; ks++)
            bq[nt][ks] = *reinterpret_cast<const bf16x8*>(
                qp + (long)(qbase + nt * 16 + l16) * DK + ks * 32 + quad * 8);

    f32x4 o[2][4];     // O[qrow-tile mt][d-tile nt]
    #pragma unroll
    for (int i = 0; i < 2; i++)
        #pragma unroll
        for (int j = 0; j < 4; j++) o[i][j] = f32x4{0.f, 0.f, 0.f, 0.f};
    float lsum[2] = {0.f, 0.f};   // per-lane partial row sums, qrow = nt*16+l16

    // prologue: tiles 0,1 into buffers 0,1 — 4 DMA issues per tile per wave
    #pragma unroll
    for (int pt = 0; pt < 2; pt++) {
        #pragma unroll
        for (int i = 0; i < 2; i++) {
            const int row = w * 16 + i * 8;
            async16(&Ks[pt][row * 64], kp + (long)(pt * 64 + row + sr) * DK + scs * 8);
            async16(&Vs[pt][row * 64], vp + (long)(row + sr) * S + pt * 64 + scs * 8);
        }
    }

    int cur = 0;
    constexpr int ITERS = S / 64;   // 32
    for (int it = 0; it < ITERS; it++) {
        if (it < ITERS - 1) asm volatile("s_waitcnt vmcnt(4)" ::: "memory");
        else                asm volatile("s_waitcnt vmcnt(0)" ::: "memory");
        asm volatile("s_barrier" ::: "memory");   // raw: no drain

        if (it + 2 < ITERS) {
            const int kt2 = (it + 2) * 64;
            const int pb  = (cur == 0) ? 2 : cur - 1;
            #pragma unroll
            for (int i = 0; i < 2; i++) {
                const int row = w * 16 + i * 8;
                async16(&Ks[pb][row * 64], kp + (long)(kt2 + row + sr) * DK + scs * 8);
                async16(&Vs[pb][row * 64], vp + (long)(row + sr) * S + kt2 + scs * 8);
            }
        }

        // ---- S^T = K Q^T : C[key(regs) 64][qrow(lanes) 32] ----
        f32x4 sacc[4][2];  // [key-tile mt][qrow-tile nt]
        #pragma unroll
        for (int i = 0; i < 4; i++)
            #pragma unroll
            for (int j = 0; j < 2; j++) sacc[i][j] = f32x4{0.f, 0.f, 0.f, 0.f};
        #pragma unroll
        for (int ks = 0; ks < 2; ks++) {
            bf16x8 ak[4];
            #pragma unroll
            for (int mt = 0; mt < 4; mt++)
                ak[mt] = *reinterpret_cast<const bf16x8*>(
                    &Ks[cur][(mt * 16 + l16) * 64 + ((ks * 4 + quad) ^ (l16 & 7)) * 8]);
            __builtin_amdgcn_s_setprio(1);
            #pragma unroll
            for (int mt = 0; mt < 4; mt++)
                #pragma unroll
                for (int nt = 0; nt < 2; nt++)
                    sacc[mt][nt] = __builtin_amdgcn_mfma_f32_16x16x32_bf16(
                        ak[mt], bq[nt][ks], sacc[mt][nt], 0, 0, 0);
            __builtin_amdgcn_s_setprio(0);
        }

        // ---- P = exp2(S^T): 4 consecutive keys (regs) -> one b64 store ----
        #pragma unroll
        for (int mt = 0; mt < 4; mt++)
            #pragma unroll
            for (int nt = 0; nt < 2; nt++) {
                float p0 = __builtin_amdgcn_exp2f(sacc[mt][nt][0]);
                float p1 = __builtin_amdgcn_exp2f(sacc[mt][nt][1]);
                float p2 = __builtin_amdgcn_exp2f(sacc[mt][nt][2]);
                float p3 = __builtin_amdgcn_exp2f(sacc[mt][nt][3]);
                lsum[nt] += (p0 + p1) + (p2 + p3);
                bf16x4 pk;
                pk[0] = (__bf16)p0; pk[1] = (__bf16)p1;
                pk[2] = (__bf16)p2; pk[3] = (__bf16)p3;
                *reinterpret_cast<bf16x4*>(
                    &Pl[w][(nt * 16 + l16) * 72 + mt * 16 + quad * 4]) = pk;
            }

        // ---- O += P V : A=P[m=qrow][k=key], B=V[k=key][n=d], 2 k-halves ----
        #pragma unroll
        for (int kh = 0; kh < 2; kh++) {
            bf16x8 bv[4];
            #pragma unroll
            for (int nt = 0; nt < 4; nt++)
                bv[nt] = *reinterpret_cast<const bf16x8*>(
                    &Vs[cur][(nt * 16 + l16) * 64 + ((kh * 4 + quad) ^ (l16 & 7)) * 8]);
            __builtin_amdgcn_s_setprio(1);
            #pragma unroll
            for (int mt = 0; mt < 2; mt++) {
                bf16x8 ap = *reinterpret_cast<const bf16x8*>(
                    &Pl[w][(mt * 16 + l16) * 72 + kh * 32 + quad * 8]);
                #pragma unroll
                for (int nt = 0; nt < 4; nt++)
                    o[mt][nt] = __builtin_amdgcn_mfma_f32_16x16x32_bf16(
                        ap, bv[nt], o[mt][nt], 0, 0, 0);
            }
            __builtin_amdgcn_s_setprio(0);
        }

        cur = (cur == 2) ? 0 : cur + 1;
    }

    // ---- finalize l: reduce partials across the 4 quads, broadcast via LDS ----
    #pragma unroll
    for (int nt = 0; nt < 2; nt++) {
        float v = lsum[nt];
        v += __shfl_xor(v, 16);
        v += __shfl_xor(v, 32);
        ls_lds[w][nt * 16 + l16] = v;   // quads duplicate-write same value (benign)
    }

    // ---- epilogue: per-wave LDS bounce -> coalesced f32x4 stores ----
    __syncthreads();   // all waves done reading Ks/Vs (loop fully consumed)
    float* scr = (w < 3) ? (float*)&Ks[w][0] : (float*)&Vs[0][0];  // 8 KB = 32x64 f32
    const int b = bh >> 4, h = bh & 15;
    #pragma unroll
    for (int mt = 0; mt < 2; mt++) {
        f32x4 lv = *reinterpret_cast<const f32x4*>(&ls_lds[w][mt * 16 + quad * 4]);
        #pragma unroll
        for (int r = 0; r < 4; r++) {
            const float inv = 1.0f / lv[r];
            const int row = mt * 16 + quad * 4 + r;       // 0..31 within wave
            #pragma unroll
            for (int nt = 0; nt < 4; nt++)
                scr[row * 64 + nt * 16 + l16] = o[mt][nt][r] * inv;
        }
    }
    __syncthreads();   // order scr writes before aliased reads
    #pragma unroll
    for (int p = 0; p < 8; p++) {
        const int c = p * 64 + lane;
        const int row = c >> 4, chunk = c & 15;           // row 0..31, 16B chunk 0..15
        f32x4 v4 = *reinterpret_cast<const f32x4*>(&scr[row * 64 + chunk * 4]);
        const int srow = qbase + row;
        *reinterpret_cast<f32x4*>(
            &out[(long)(b * S + srow) * E + h * DK + chunk * 4]) = v4;
    }
}

extern "C" void kernel_launch(void* const* d_in, const int* in_sizes, int n_in,
                              void* d_out, int out_size, void* d_ws, size_t ws_size,
                              hipStream_t stream) {
    const float* x     = (const float*)d_in[0];
    const float* Wk    = (const float*)d_in[1];
    const float* Wv    = (const float*)d_in[2];
    const float* Wq    = (const float*)d_in[3];
    const float* theta = (const float*)d_in[4];
    float* out = (float*)d_out;

    // ws: kvq[3*RSZ: K | V^T | Q] -- 25.2 MB. d_out doubles as scratch for
    // xb (8.4 MB) + wall (6.3 MB) during cvt+qkv; attn fully overwrites it.
    __bf16* kvq  = (__bf16*)d_ws;
    __bf16* k_ws = kvq;
    __bf16* v_t  = kvq + RSZ;
    __bf16* q_ws = kvq + 2 * RSZ;
    __bf16* xb   = (__bf16*)d_out;
    __bf16* wall = xb + (long)M * E;

    cvt_kernel<<<dim3(1792), dim3(256), 0, stream>>>(x, Wk, Wv, Wq, xb, wall);
    qkv_gemm<<<dim3(192), dim3(512), 0, stream>>>(xb, wall, theta, kvq);
    attn_kernel<<<dim3(512), dim3(256), 0, stream>>>(q_ws, k_ws, v_t, out);
}